// Round 5
// baseline (330.666 us; speedup 1.0000x reference)
//
#include <hip/hip_runtime.h>

#define BB 2
#define HH 16
#define SS 2048
#define DD 64

constexpr int OSIZE = BB * HH * SS * DD;  // 4,194,304
constexpr float LOG2E = 1.4426950408889634f;

using bf16x8 = __attribute__((ext_vector_type(8))) short;
using f32x4  = __attribute__((ext_vector_type(4))) float;
using u16x8  = __attribute__((ext_vector_type(8))) unsigned short;
using u16x4  = __attribute__((ext_vector_type(4))) unsigned short;
using fl4    = __attribute__((ext_vector_type(4))) float;

__device__ __forceinline__ unsigned short f2bf(float f) {
    unsigned int u = __float_as_uint(f);
    return (unsigned short)((u + 0x7fffu + ((u >> 16) & 1u)) >> 16);
}

__device__ __forceinline__ void atomicMaxPosF(float* addr, float v) {
    atomicMax(reinterpret_cast<unsigned int*>(addr), __float_as_uint(v));
}

// ---- fused prepass: amax init + K->bf16 convert + V->bf16 transpose ----
__global__ __launch_bounds__(256) void prep_kv_kernel(
    const float* __restrict__ k, const float* __restrict__ v,
    const float* __restrict__ dsk, const float* __restrict__ dsv,
    unsigned short* __restrict__ kbf, unsigned short* __restrict__ vtb,
    float* __restrict__ out)
{
    const int t  = threadIdx.x;
    const int s0 = blockIdx.x * 64;
    const int bh = blockIdx.y;
    if (blockIdx.x == 0 && bh == 0 && t < 2) out[OSIZE + t] = 0.0f;

    const size_t base = (size_t)bh * SS * DD;
    const float sck = dsk[0], scv = dsv[0];

    // K convert: 64x64 chunk, 16 contiguous elems/thread
    {
        const float* kp = k + base + (size_t)s0 * DD + t * 16;
        unsigned short* ko = kbf + base + (size_t)s0 * DD + t * 16;
        fl4 a0 = ((const fl4*)kp)[0], a1 = ((const fl4*)kp)[1];
        fl4 a2 = ((const fl4*)kp)[2], a3 = ((const fl4*)kp)[3];
        u16x8 o0, o1;
        #pragma unroll
        for (int j = 0; j < 4; ++j) {
            o0[j] = f2bf(a0[j] * sck); o0[j + 4] = f2bf(a1[j] * sck);
            o1[j] = f2bf(a2[j] * sck); o1[j + 4] = f2bf(a3[j] * sck);
        }
        ((u16x8*)ko)[0] = o0; ((u16x8*)ko)[1] = o1;
    }

    // V transpose via LDS: [s][d] -> [d][s]
    __shared__ unsigned short T[64 * 72];
    {
        const int r  = t >> 2;
        const int cb = (t & 3) * 16;
        const fl4* vp = (const fl4*)(v + base + (size_t)(s0 + r) * DD + cb);
        unsigned short tmp[16];
        #pragma unroll
        for (int c = 0; c < 4; ++c) {
            fl4 x = vp[c];
            #pragma unroll
            for (int j = 0; j < 4; ++j) tmp[c * 4 + j] = f2bf(x[j] * scv);
        }
        *(u16x8*)&T[r * 72 + cb]     = *(u16x8*)&tmp[0];
        *(u16x8*)&T[r * 72 + cb + 8] = *(u16x8*)&tmp[8];
    }
    __syncthreads();
    {
        const int dr = t >> 2;
        const int sb = (t & 3) * 16;
        unsigned short tmp[16];
        #pragma unroll
        for (int j = 0; j < 16; ++j) tmp[j] = T[(sb + j) * 72 + dr];
        unsigned short* op = vtb + base + (size_t)dr * SS + s0 + sb;
        *(u16x8*)op       = *(u16x8*)&tmp[0];
        *(u16x8*)(op + 8) = *(u16x8*)&tmp[8];
    }
}

// ---- main kernel: barrier-free, fixed-base softmax, 1 strip/wave, 1024 blocks ----
__global__ __launch_bounds__(256, 4) void fattn_kernel(
    const float* __restrict__ q,
    const unsigned short* __restrict__ kbf,     // bf16 K  [bh][s][d], dsk folded
    const unsigned short* __restrict__ vtb,     // bf16 V^T [bh][d][s], dsv folded
    const float* __restrict__ dsq, const float* __restrict__ qss,
    const float* __restrict__ qso, const float* __restrict__ dss,
    float* __restrict__ out)
{
    const int xr = blockIdx.x;                                // 0..31
    const int qt = (xr & 1) ? (31 - (xr >> 1)) : (xr >> 1);   // balanced interleave
    const int bh = blockIdx.y;
    const int tid  = threadIdx.x;
    const int wave = tid >> 6;
    const int lane = tid & 63;
    const int m16  = lane & 15;
    const int quad = lane >> 4;
    const int m7   = m16 & 7;

    // LDS: per-wave P scratch only (8 KB total, no barriers anywhere)
    __shared__ __align__(16) unsigned short Psh[4][16 * 64];

    const float q_scale = dsq[0] * 0.125f * LOG2E;
    const size_t base = (size_t)bh * SS * DD;
    const int qb = qt * 64;

    // Q fragment (B operand), prescaled, log2e folded
    bf16x8 qf[2];
    {
        const int qrow = qb + wave * 16 + m16;
        const float* qp = q + base + (size_t)qrow * DD + quad * 8;
        #pragma unroll
        for (int f = 0; f < 2; ++f) {
            fl4 a = *(const fl4*)(qp + f * 32);
            fl4 b = *(const fl4*)(qp + f * 32 + 4);
            #pragma unroll
            for (int j = 0; j < 4; ++j) {
                qf[f][j]     = (short)f2bf(a[j] * q_scale);
                qf[f][j + 4] = (short)f2bf(b[j] * q_scale);
            }
        }
    }

    f32x4 Oacc[4];
    #pragma unroll
    for (int dt = 0; dt < 4; ++dt)
        #pragma unroll
        for (int r = 0; r < 4; ++r) Oacc[dt][r] = 0.0f;

    // fixed-base softmax state: per-lane partials, reduced once at epilogue
    float l_lane = 0.0f;   // sum of e over this lane's columns (row q = m16)
    float e_max  = 0.0f;   // max e over this lane's columns  (row q = m16)

    const int gsw0 = (quad ^ m7) * 8;   // swizzled granule offsets (P reads)
    const int gsw1 = ((4 | quad) ^ m7) * 8;

    // fragment base pointers
    const unsigned short* kp = kbf + base + (size_t)m16 * DD + quad * 8;
    const unsigned short* vp = vtb + base + (size_t)m16 * SS + quad * 8;

    const int nkt = qt + 1;

    for (int t = 0; t < nkt; ++t) {
        const int kb = t * 64;

        // ---- direct global->register fragment loads (L2-resident, 16B/lane) ----
        bf16x8 kf[4][2], vf[4][2];
        #pragma unroll
        for (int nt = 0; nt < 4; ++nt) {
            const unsigned short* kr = kp + (size_t)(kb + nt * 16) * DD;
            kf[nt][0] = *(const bf16x8*)kr;
            kf[nt][1] = *(const bf16x8*)(kr + 32);
        }
        #pragma unroll
        for (int dt = 0; dt < 4; ++dt) {
            const unsigned short* vr = vp + (size_t)(dt * 16) * SS + kb;
            vf[dt][0] = *(const bf16x8*)vr;
            vf[dt][1] = *(const bf16x8*)(vr + 32);
        }

        // ---- S^T = K Q^T : C[row=k=quad*4+r][col=q=m16] ----
        f32x4 sacc[4];
        #pragma unroll
        for (int nt = 0; nt < 4; ++nt) {
            f32x4 acc = {0.0f, 0.0f, 0.0f, 0.0f};
            acc = __builtin_amdgcn_mfma_f32_16x16x32_bf16(kf[nt][0], qf[0], acc, 0, 0, 0);
            acc = __builtin_amdgcn_mfma_f32_16x16x32_bf16(kf[nt][1], qf[1], acc, 0, 0, 0);
            sacc[nt] = acc;
        }

        // ---- causal mask on the diagonal tile ----
        if (t == nkt - 1) {
            const int qg = qb + wave * 16 + m16;
            #pragma unroll
            for (int nt = 0; nt < 4; ++nt)
                #pragma unroll
                for (int r = 0; r < 4; ++r) {
                    const int kc = kb + nt * 16 + quad * 4 + r;
                    if (kc > qg) sacc[nt][r] = -1.0e30f;
                }
        }

        // ---- fixed-base softmax: e = 2^S (base cancels in p = e/l); no reductions ----
        #pragma unroll
        for (int nt = 0; nt < 4; ++nt)
            #pragma unroll
            for (int r = 0; r < 4; ++r) {
                const float e = __builtin_amdgcn_exp2f(sacc[nt][r]);
                sacc[nt][r] = e;
                e_max  = fmaxf(e_max, e);
                l_lane += e;
            }

        // ---- P: C-layout -> A-layout via swizzled per-wave LDS (no barrier) ----
        unsigned short* P = &Psh[wave][0];
        #pragma unroll
        for (int nt = 0; nt < 4; ++nt) {
            u16x4 pk;
            #pragma unroll
            for (int r = 0; r < 4; ++r) pk[r] = f2bf(sacc[nt][r]);
            const int g = nt * 2 + (quad >> 1);
            *(u16x4*)&P[m16 * 64 + ((g ^ m7) * 8) + (quad & 1) * 4] = pk;
        }
        bf16x8 pf0 = *(const bf16x8*)&P[m16 * 64 + gsw0];
        bf16x8 pf1 = *(const bf16x8*)&P[m16 * 64 + gsw1];

        // ---- O += E V (unnormalized; divide by l at the end) ----
        #pragma unroll
        for (int dt = 0; dt < 4; ++dt) {
            Oacc[dt] = __builtin_amdgcn_mfma_f32_16x16x32_bf16(pf0, vf[dt][0], Oacc[dt], 0, 0, 0);
            Oacc[dt] = __builtin_amdgcn_mfma_f32_16x16x32_bf16(pf1, vf[dt][1], Oacc[dt], 0, 0, 0);
        }
    }

    // ---- epilogue: one-time reductions, normalize, store, amax ----
    float l = l_lane;
    l += __shfl_xor(l, 16);
    l += __shfl_xor(l, 32);
    float em = e_max;
    em = fmaxf(em, __shfl_xor(em, 16));
    em = fmaxf(em, __shfl_xor(em, 32));
    float amax_s = em / l;   // max softmax prob for row q = m16

    const float ss_ = qss[0] * dss[0];
    const float o_q = qso[0];
    float amax_o = 0.0f;
    #pragma unroll
    for (int r = 0; r < 4; ++r) {
        const float lr  = __shfl(l, (lane & 48) | (quad * 4 + r));
        const float ivl = ss_ / lr;
        const int row = qb + wave * 16 + quad * 4 + r;
        float* op = out + base + (size_t)row * DD + m16;
        #pragma unroll
        for (int dt = 0; dt < 4; ++dt) {
            const float o_raw = Oacc[dt][r] * ivl;
            amax_o = fmaxf(amax_o, fabsf(o_raw));
            op[dt * 16] = o_raw * o_q;
        }
    }
    #pragma unroll
    for (int m = 1; m < 64; m <<= 1) {
        amax_o = fmaxf(amax_o, __shfl_xor(amax_o, m));
        amax_s = fmaxf(amax_s, __shfl_xor(amax_s, m));
    }
    if (lane == 0) {
        atomicMaxPosF(out + OSIZE,     amax_s);
        atomicMaxPosF(out + OSIZE + 1, amax_o);
    }
}

extern "C" void kernel_launch(void* const* d_in, const int* in_sizes, int n_in,
                              void* d_out, int out_size, void* d_ws, size_t ws_size,
                              hipStream_t stream) {
    const float* q   = (const float*)d_in[0];
    const float* k   = (const float*)d_in[1];
    const float* v   = (const float*)d_in[2];
    const float* dsq = (const float*)d_in[3];
    const float* dsk = (const float*)d_in[4];
    const float* dsv = (const float*)d_in[5];
    const float* qss = (const float*)d_in[6];
    const float* qso = (const float*)d_in[7];
    const float* dss = (const float*)d_in[8];
    float* out = (float*)d_out;

    unsigned short* kbf = (unsigned short*)d_ws;            // 8 MB
    unsigned short* vtb = (unsigned short*)d_ws + OSIZE;    // 8 MB

    prep_kv_kernel<<<dim3(SS / 64, BB * HH), 256, 0, stream>>>(k, v, dsk, dsv, kbf, vtb, out);

    dim3 grid(SS / 64, BB * HH);   // (32, 32), qt remapped inside
    fattn_kernel<<<grid, 256, 0, stream>>>(q, kbf, vtb, dsq, qss, qso, dss, out);
}

// Round 6
// 205.520 us; speedup vs baseline: 1.6089x; 1.6089x over previous
//
#include <hip/hip_runtime.h>

#define BB 2
#define HH 16
#define SS 2048
#define DD 64

constexpr int OSIZE = BB * HH * SS * DD;  // 4,194,304
constexpr float LOG2E = 1.4426950408889634f;

using bf16x8 = __attribute__((ext_vector_type(8))) short;
using f32x4  = __attribute__((ext_vector_type(4))) float;
using u16x8  = __attribute__((ext_vector_type(8))) unsigned short;
using u16x4  = __attribute__((ext_vector_type(4))) unsigned short;
using fl4    = __attribute__((ext_vector_type(4))) float;

__device__ __forceinline__ unsigned short f2bf(float f) {
    unsigned int u = __float_as_uint(f);
    return (unsigned short)((u + 0x7fffu + ((u >> 16) & 1u)) >> 16);
}

__device__ __forceinline__ void atomicMaxPosF(float* addr, float v) {
    atomicMax(reinterpret_cast<unsigned int*>(addr), __float_as_uint(v));
}

// ---- fused prepass: amax init + K->bf16 convert + V->bf16 transpose ----
__global__ __launch_bounds__(256) void prep_kv_kernel(
    const float* __restrict__ k, const float* __restrict__ v,
    const float* __restrict__ dsk, const float* __restrict__ dsv,
    unsigned short* __restrict__ kbf, unsigned short* __restrict__ vtb,
    float* __restrict__ out)
{
    const int t  = threadIdx.x;
    const int s0 = blockIdx.x * 64;
    const int bh = blockIdx.y;
    if (blockIdx.x == 0 && bh == 0 && t < 2) out[OSIZE + t] = 0.0f;

    const size_t base = (size_t)bh * SS * DD;
    const float sck = dsk[0], scv = dsv[0];

    // K convert: 64x64 chunk, 16 contiguous elems/thread
    {
        const float* kp = k + base + (size_t)s0 * DD + t * 16;
        unsigned short* ko = kbf + base + (size_t)s0 * DD + t * 16;
        fl4 a0 = ((const fl4*)kp)[0], a1 = ((const fl4*)kp)[1];
        fl4 a2 = ((const fl4*)kp)[2], a3 = ((const fl4*)kp)[3];
        u16x8 o0, o1;
        #pragma unroll
        for (int j = 0; j < 4; ++j) {
            o0[j] = f2bf(a0[j] * sck); o0[j + 4] = f2bf(a1[j] * sck);
            o1[j] = f2bf(a2[j] * sck); o1[j + 4] = f2bf(a3[j] * sck);
        }
        ((u16x8*)ko)[0] = o0; ((u16x8*)ko)[1] = o1;
    }

    // V transpose via LDS: [s][d] -> [d][s]
    __shared__ unsigned short T[64 * 72];
    {
        const int r  = t >> 2;
        const int cb = (t & 3) * 16;
        const fl4* vp = (const fl4*)(v + base + (size_t)(s0 + r) * DD + cb);
        unsigned short tmp[16];
        #pragma unroll
        for (int c = 0; c < 4; ++c) {
            fl4 x = vp[c];
            #pragma unroll
            for (int j = 0; j < 4; ++j) tmp[c * 4 + j] = f2bf(x[j] * scv);
        }
        *(u16x8*)&T[r * 72 + cb]     = *(u16x8*)&tmp[0];
        *(u16x8*)&T[r * 72 + cb + 8] = *(u16x8*)&tmp[8];
    }
    __syncthreads();
    {
        const int dr = t >> 2;
        const int sb = (t & 3) * 16;
        unsigned short tmp[16];
        #pragma unroll
        for (int j = 0; j < 16; ++j) tmp[j] = T[(sb + j) * 72 + dr];
        unsigned short* op = vtb + base + (size_t)dr * SS + s0 + sb;
        *(u16x8*)op       = *(u16x8*)&tmp[0];
        *(u16x8*)(op + 8) = *(u16x8*)&tmp[8];
    }
}

// ---- main kernel: coop staging, register-prefetch dbuf, 1 barrier/tile ----
__global__ __launch_bounds__(256, 4) void fattn_kernel(
    const float* __restrict__ q,
    const unsigned short* __restrict__ kbf,     // bf16 K  [bh][s][d], dsk folded
    const unsigned short* __restrict__ vtb,     // bf16 V^T [bh][d][s], dsv folded
    const float* __restrict__ dsq, const float* __restrict__ qss,
    const float* __restrict__ qso, const float* __restrict__ dss,
    float* __restrict__ out)
{
    const int xr = blockIdx.x;                                // 0..31
    const int qt = (xr & 1) ? (31 - (xr >> 1)) : (xr >> 1);   // balanced interleave
    const int bh = blockIdx.y;
    const int tid  = threadIdx.x;
    const int wave = tid >> 6;
    const int lane = tid & 63;
    const int m16  = lane & 15;
    const int quad = lane >> 4;
    const int m7   = m16 & 7;

    // LDS: K dbuf 16K + V dbuf 16K + P 8K = 40960 B -> exactly 4 blocks/CU
    __shared__ __align__(16) unsigned short Ksh[2][64 * 64];
    __shared__ __align__(16) unsigned short Vsh[2][64 * 64];
    __shared__ __align__(16) unsigned short Psh[4][16 * 64];

    const float q_scale = dsq[0] * 0.125f * LOG2E;
    const size_t base = (size_t)bh * SS * DD;
    const unsigned short* kbh = kbf + base;
    const unsigned short* vbh = vtb + base;
    const int qb = qt * 64;

    // cooperative staging geometry: thread stages LDS granule slots tid and tid+256;
    // source granule column is XOR-swizzled so LDS (r,c) holds global (r, c^(r&7))
    const int kr0  = tid >> 3;                       // rows 0..31
    const int kcs  = ((tid & 7) ^ (kr0 & 7)) * 8;    // same for row kr0+32 (bit3 unchanged in &7? kr0+32 keeps low 3 bits)
    const int koff0 = kr0 * DD + kcs, koff1 = koff0 + 32 * DD;
    const int voff0 = kr0 * SS + kcs, voff1 = voff0 + 32 * SS;
    const int lds0 = tid * 8, lds1 = (tid + 256) * 8;

    // Q fragment (B operand), prescaled, log2e folded
    bf16x8 qf[2];
    {
        const int qrow = qb + wave * 16 + m16;
        const float* qp = q + base + (size_t)qrow * DD + quad * 8;
        #pragma unroll
        for (int f = 0; f < 2; ++f) {
            fl4 a = *(const fl4*)(qp + f * 32);
            fl4 b = *(const fl4*)(qp + f * 32 + 4);
            #pragma unroll
            for (int j = 0; j < 4; ++j) {
                qf[f][j]     = (short)f2bf(a[j] * q_scale);
                qf[f][j + 4] = (short)f2bf(b[j] * q_scale);
            }
        }
    }

    f32x4 Oacc[4];
    #pragma unroll
    for (int dt = 0; dt < 4; ++dt)
        #pragma unroll
        for (int r = 0; r < 4; ++r) Oacc[dt][r] = 0.0f;

    float l_lane = 0.0f, e_max = 0.0f;   // fixed-base softmax state (row q = m16)

    const int gsw0 = (quad ^ m7) * 8;    // swizzled granule offsets for frag reads
    const int gsw1 = ((4 | quad) ^ m7) * 8;

    const int nkt = qt + 1;

    // prologue: stage tile 0 into buffer 0
    {
        u16x8 k0 = *(const u16x8*)(kbh + koff0);
        u16x8 k1 = *(const u16x8*)(kbh + koff1);
        u16x8 v0 = *(const u16x8*)(vbh + voff0);
        u16x8 v1 = *(const u16x8*)(vbh + voff1);
        *(u16x8*)&Ksh[0][lds0] = k0; *(u16x8*)&Ksh[0][lds1] = k1;
        *(u16x8*)&Vsh[0][lds0] = v0; *(u16x8*)&Vsh[0][lds1] = v1;
    }
    __syncthreads();

    for (int t = 0; t < nkt; ++t) {
        const int b = t & 1;
        const bool pf = (t + 1 < nkt);

        // issue prefetch for tile t+1 (latency hidden behind this tile's compute)
        u16x8 kp0, kp1, vp0, vp1;
        if (pf) {
            const unsigned short* kg = kbh + (size_t)(t + 1) * 64 * DD;
            const unsigned short* vg = vbh + (t + 1) * 64;
            kp0 = *(const u16x8*)(kg + koff0);
            kp1 = *(const u16x8*)(kg + koff1);
            vp0 = *(const u16x8*)(vg + voff0);
            vp1 = *(const u16x8*)(vg + voff1);
        }

        const unsigned short* Kt = &Ksh[b][0];
        const unsigned short* Vt = &Vsh[b][0];

        // S^T = K Q^T : C[row=k=quad*4+r][col=q=m16]
        f32x4 sacc[4];
        #pragma unroll
        for (int nt = 0; nt < 4; ++nt) {
            f32x4 acc = {0.0f, 0.0f, 0.0f, 0.0f};
            const int rb = (nt * 16 + m16) * 64;
            bf16x8 kf0 = *(const bf16x8*)&Kt[rb + gsw0];
            bf16x8 kf1 = *(const bf16x8*)&Kt[rb + gsw1];
            acc = __builtin_amdgcn_mfma_f32_16x16x32_bf16(kf0, qf[0], acc, 0, 0, 0);
            acc = __builtin_amdgcn_mfma_f32_16x16x32_bf16(kf1, qf[1], acc, 0, 0, 0);
            sacc[nt] = acc;
        }

        // causal mask on the diagonal tile
        if (t == nkt - 1) {
            const int qg = qb + wave * 16 + m16;
            const int kb = t * 64;
            #pragma unroll
            for (int nt = 0; nt < 4; ++nt)
                #pragma unroll
                for (int r = 0; r < 4; ++r) {
                    const int kc = kb + nt * 16 + quad * 4 + r;
                    if (kc > qg) sacc[nt][r] = -1.0e30f;
                }
        }

        // fixed-base softmax: e = 2^S (base cancels in p = e/l); no reductions
        #pragma unroll
        for (int nt = 0; nt < 4; ++nt)
            #pragma unroll
            for (int r = 0; r < 4; ++r) {
                const float e = __builtin_amdgcn_exp2f(sacc[nt][r]);
                sacc[nt][r] = e;
                e_max  = fmaxf(e_max, e);
                l_lane += e;
            }

        // P: C-layout -> A-layout via swizzled per-wave LDS (wave-internal)
        unsigned short* P = &Psh[wave][0];
        #pragma unroll
        for (int nt = 0; nt < 4; ++nt) {
            u16x4 pk;
            #pragma unroll
            for (int r = 0; r < 4; ++r) pk[r] = f2bf(sacc[nt][r]);
            const int g = nt * 2 + (quad >> 1);
            *(u16x4*)&P[m16 * 64 + ((g ^ m7) * 8) + (quad & 1) * 4] = pk;
        }
        bf16x8 pf0 = *(const bf16x8*)&P[m16 * 64 + gsw0];
        bf16x8 pf1 = *(const bf16x8*)&P[m16 * 64 + gsw1];

        // O += E V (unnormalized)
        #pragma unroll
        for (int dt = 0; dt < 4; ++dt) {
            const int rb = (dt * 16 + m16) * 64;
            bf16x8 vf0 = *(const bf16x8*)&Vt[rb + gsw0];
            bf16x8 vf1 = *(const bf16x8*)&Vt[rb + gsw1];
            Oacc[dt] = __builtin_amdgcn_mfma_f32_16x16x32_bf16(pf0, vf0, Oacc[dt], 0, 0, 0);
            Oacc[dt] = __builtin_amdgcn_mfma_f32_16x16x32_bf16(pf1, vf1, Oacc[dt], 0, 0, 0);
        }

        // commit prefetched tile to the other buffer (vmcnt wait lands here, late)
        if (pf) {
            *(u16x8*)&Ksh[b ^ 1][lds0] = kp0; *(u16x8*)&Ksh[b ^ 1][lds1] = kp1;
            *(u16x8*)&Vsh[b ^ 1][lds0] = vp0; *(u16x8*)&Vsh[b ^ 1][lds1] = vp1;
        }
        __syncthreads();
    }

    // epilogue: one-time reductions, normalize, store, amax
    float l = l_lane;
    l += __shfl_xor(l, 16);
    l += __shfl_xor(l, 32);
    float em = e_max;
    em = fmaxf(em, __shfl_xor(em, 16));
    em = fmaxf(em, __shfl_xor(em, 32));
    float amax_s = em / l;   // max softmax prob for row q = m16

    const float ss_ = qss[0] * dss[0];
    const float o_q = qso[0];
    float amax_o = 0.0f;
    #pragma unroll
    for (int r = 0; r < 4; ++r) {
        const float lr  = __shfl(l, (lane & 48) | (quad * 4 + r));
        const float ivl = ss_ / lr;
        const int row = qb + wave * 16 + quad * 4 + r;
        float* op = out + base + (size_t)row * DD + m16;
        #pragma unroll
        for (int dt = 0; dt < 4; ++dt) {
            const float o_raw = Oacc[dt][r] * ivl;
            amax_o = fmaxf(amax_o, fabsf(o_raw));
            op[dt * 16] = o_raw * o_q;
        }
    }
    #pragma unroll
    for (int m = 1; m < 64; m <<= 1) {
        amax_o = fmaxf(amax_o, __shfl_xor(amax_o, m));
        amax_s = fmaxf(amax_s, __shfl_xor(amax_s, m));
    }
    if (lane == 0) {
        atomicMaxPosF(out + OSIZE,     amax_s);
        atomicMaxPosF(out + OSIZE + 1, amax_o);
    }
}

extern "C" void kernel_launch(void* const* d_in, const int* in_sizes, int n_in,
                              void* d_out, int out_size, void* d_ws, size_t ws_size,
                              hipStream_t stream) {
    const float* q   = (const float*)d_in[0];
    const float* k   = (const float*)d_in[1];
    const float* v   = (const float*)d_in[2];
    const float* dsq = (const float*)d_in[3];
    const float* dsk = (const float*)d_in[4];
    const float* dsv = (const float*)d_in[5];
    const float* qss = (const float*)d_in[6];
    const float* qso = (const float*)d_in[7];
    const float* dss = (const float*)d_in[8];
    float* out = (float*)d_out;

    unsigned short* kbf = (unsigned short*)d_ws;            // 8 MB
    unsigned short* vtb = (unsigned short*)d_ws + OSIZE;    // 8 MB

    prep_kv_kernel<<<dim3(SS / 64, BB * HH), 256, 0, stream>>>(k, v, dsk, dsv, kbf, vtb, out);

    dim3 grid(SS / 64, BB * HH);   // (32, 32), qt remapped inside
    fattn_kernel<<<grid, 256, 0, stream>>>(q, kbf, vtb, dsq, qss, qso, dss, out);
}

// Round 7
// 184.457 us; speedup vs baseline: 1.7926x; 1.1142x over previous
//
#include <hip/hip_runtime.h>

#define BB 2
#define HH 16
#define SS 2048
#define DD 64

constexpr int OSIZE = BB * HH * SS * DD;  // 4,194,304
constexpr float LOG2E = 1.4426950408889634f;

using bf16x8 = __attribute__((ext_vector_type(8))) short;
using f32x4  = __attribute__((ext_vector_type(4))) float;
using u16x8  = __attribute__((ext_vector_type(8))) unsigned short;
using u32x2  = __attribute__((ext_vector_type(2))) unsigned int;
using fl4    = __attribute__((ext_vector_type(4))) float;

__device__ __forceinline__ unsigned short f2bf(float f) {
    unsigned int u = __float_as_uint(f);
    return (unsigned short)((u + 0x7fffu + ((u >> 16) & 1u)) >> 16);
}

// pack two fp32 -> (bf16_hi<<16)|bf16_lo via one v_perm_b32 (truncation)
__device__ __forceinline__ unsigned int pkbf(float lo, float hi) {
    return __builtin_amdgcn_perm(__float_as_uint(hi), __float_as_uint(lo), 0x07060302u);
}

__device__ __forceinline__ void atomicMaxPosF(float* addr, float v) {
    atomicMax(reinterpret_cast<unsigned int*>(addr), __float_as_uint(v));
}

// ---- fused prepass: amax init + K->bf16 convert + V->bf16 transpose ----
__global__ __launch_bounds__(256) void prep_kv_kernel(
    const float* __restrict__ k, const float* __restrict__ v,
    const float* __restrict__ dsk, const float* __restrict__ dsv,
    unsigned short* __restrict__ kbf, unsigned short* __restrict__ vtb,
    float* __restrict__ out)
{
    const int t  = threadIdx.x;
    const int s0 = blockIdx.x * 64;
    const int bh = blockIdx.y;
    if (blockIdx.x == 0 && bh == 0 && t < 2) out[OSIZE + t] = 0.0f;

    const size_t base = (size_t)bh * SS * DD;
    const float sck = dsk[0], scv = dsv[0];

    // K convert: 64x64 chunk, 16 contiguous elems/thread
    {
        const float* kp = k + base + (size_t)s0 * DD + t * 16;
        unsigned short* ko = kbf + base + (size_t)s0 * DD + t * 16;
        fl4 a0 = ((const fl4*)kp)[0], a1 = ((const fl4*)kp)[1];
        fl4 a2 = ((const fl4*)kp)[2], a3 = ((const fl4*)kp)[3];
        u16x8 o0, o1;
        #pragma unroll
        for (int j = 0; j < 4; ++j) {
            o0[j] = f2bf(a0[j] * sck); o0[j + 4] = f2bf(a1[j] * sck);
            o1[j] = f2bf(a2[j] * sck); o1[j + 4] = f2bf(a3[j] * sck);
        }
        ((u16x8*)ko)[0] = o0; ((u16x8*)ko)[1] = o1;
    }

    // V transpose via LDS: [s][d] -> [d][s]
    __shared__ unsigned short T[64 * 72];
    {
        const int r  = t >> 2;
        const int cb = (t & 3) * 16;
        const fl4* vp = (const fl4*)(v + base + (size_t)(s0 + r) * DD + cb);
        unsigned short tmp[16];
        #pragma unroll
        for (int c = 0; c < 4; ++c) {
            fl4 x = vp[c];
            #pragma unroll
            for (int j = 0; j < 4; ++j) tmp[c * 4 + j] = f2bf(x[j] * scv);
        }
        *(u16x8*)&T[r * 72 + cb]     = *(u16x8*)&tmp[0];
        *(u16x8*)&T[r * 72 + cb + 8] = *(u16x8*)&tmp[8];
    }
    __syncthreads();
    {
        const int dr = t >> 2;
        const int sb = (t & 3) * 16;
        unsigned short tmp[16];
        #pragma unroll
        for (int j = 0; j < 16; ++j) tmp[j] = T[(sb + j) * 72 + dr];
        unsigned short* op = vtb + base + (size_t)dr * SS + s0 + sb;
        *(u16x8*)op       = *(u16x8*)&tmp[0];
        *(u16x8*)(op + 8) = *(u16x8*)&tmp[8];
    }
}

// ---- main kernel: uniform-work blocks (qt pair {x, 31-x}), dbuf staging ----
__global__ __launch_bounds__(256, 4) void fattn_kernel(
    const float* __restrict__ q,
    const unsigned short* __restrict__ kbf,     // bf16 K  [bh][s][d], dsk folded
    const unsigned short* __restrict__ vtb,     // bf16 V^T [bh][d][s], dsv folded
    const float* __restrict__ dsq, const float* __restrict__ qss,
    const float* __restrict__ qso, const float* __restrict__ dss,
    float* __restrict__ out)
{
    const int x  = blockIdx.x;                  // 0..15
    const int bh = blockIdx.y;
    const int tid  = threadIdx.x;
    const int wave = tid >> 6;
    const int lane = tid & 63;
    const int m16  = lane & 15;
    const int quad = lane >> 4;
    const int m7   = m16 & 7;

    // LDS: K dbuf 16K + V dbuf 16K + P 8K = 40960 B
    __shared__ __align__(16) unsigned short Ksh[2][64 * 64];
    __shared__ __align__(16) unsigned short Vsh[2][64 * 64];
    __shared__ __align__(16) unsigned short Psh[4][16 * 64];

    const float q_scale = dsq[0] * 0.125f * LOG2E;
    const size_t base = (size_t)bh * SS * DD;
    const unsigned short* kbh = kbf + base;
    const unsigned short* vbh = vtb + base;

    // cooperative staging geometry (XOR-swizzled source granule)
    const int kr0  = tid >> 3;
    const int kcs  = ((tid & 7) ^ (kr0 & 7)) * 8;
    const int koff0 = kr0 * DD + kcs, koff1 = koff0 + 32 * DD;
    const int voff0 = kr0 * SS + kcs, voff1 = voff0 + 32 * SS;
    const int lds0 = tid * 8, lds1 = (tid + 256) * 8;

    const int gsw0 = (quad ^ m7) * 8;          // swizzled frag-read offsets
    const int gsw1 = ((4 | quad) ^ m7) * 8;

    const float ss_ = qss[0] * dss[0];
    const float o_q = qso[0];
    float amax_o = 0.0f, amax_s = 0.0f;

    #pragma unroll
    for (int pass = 0; pass < 2; ++pass) {
        const int qt = pass ? (31 - x) : x;     // pair work = 33 tiles, uniform
        const int qb = qt * 64;
        const int nkt = qt + 1;

        // Q fragment (B operand), prescaled
        bf16x8 qf[2];
        {
            const int qrow = qb + wave * 16 + m16;
            const float* qp = q + base + (size_t)qrow * DD + quad * 8;
            #pragma unroll
            for (int f = 0; f < 2; ++f) {
                fl4 a = *(const fl4*)(qp + f * 32);
                fl4 b = *(const fl4*)(qp + f * 32 + 4);
                #pragma unroll
                for (int j = 0; j < 4; ++j) {
                    qf[f][j]     = (short)f2bf(a[j] * q_scale);
                    qf[f][j + 4] = (short)f2bf(b[j] * q_scale);
                }
            }
        }

        f32x4 Oacc[4];
        #pragma unroll
        for (int dt = 0; dt < 4; ++dt)
            #pragma unroll
            for (int r = 0; r < 4; ++r) Oacc[dt][r] = 0.0f;

        float l_lane = 0.0f, e_max = 0.0f;

        // stage tile 0 into buffer 0
        {
            u16x8 k0 = *(const u16x8*)(kbh + koff0);
            u16x8 k1 = *(const u16x8*)(kbh + koff1);
            u16x8 v0 = *(const u16x8*)(vbh + voff0);
            u16x8 v1 = *(const u16x8*)(vbh + voff1);
            *(u16x8*)&Ksh[0][lds0] = k0; *(u16x8*)&Ksh[0][lds1] = k1;
            *(u16x8*)&Vsh[0][lds0] = v0; *(u16x8*)&Vsh[0][lds1] = v1;
        }
        __syncthreads();

        for (int t = 0; t < nkt; ++t) {
            const int b = t & 1;
            const bool pf = (t + 1 < nkt);

            u16x8 kp0, kp1, vp0, vp1;
            if (pf) {
                const unsigned short* kg = kbh + (size_t)(t + 1) * 64 * DD;
                const unsigned short* vg = vbh + (t + 1) * 64;
                kp0 = *(const u16x8*)(kg + koff0);
                kp1 = *(const u16x8*)(kg + koff1);
                vp0 = *(const u16x8*)(vg + voff0);
                vp1 = *(const u16x8*)(vg + voff1);
            }

            const unsigned short* Kt = &Ksh[b][0];
            const unsigned short* Vt = &Vsh[b][0];

            // S^T = K Q^T : C[row=k=quad*4+r][col=q=m16]
            f32x4 sacc[4];
            #pragma unroll
            for (int nt = 0; nt < 4; ++nt) {
                f32x4 acc = {0.0f, 0.0f, 0.0f, 0.0f};
                const int rb = (nt * 16 + m16) * 64;
                bf16x8 kf0 = *(const bf16x8*)&Kt[rb + gsw0];
                bf16x8 kf1 = *(const bf16x8*)&Kt[rb + gsw1];
                acc = __builtin_amdgcn_mfma_f32_16x16x32_bf16(kf0, qf[0], acc, 0, 0, 0);
                acc = __builtin_amdgcn_mfma_f32_16x16x32_bf16(kf1, qf[1], acc, 0, 0, 0);
                sacc[nt] = acc;
            }

            // causal mask on the diagonal tile
            if (t == nkt - 1) {
                const int qg = qb + wave * 16 + m16;
                const int kb = t * 64;
                #pragma unroll
                for (int nt = 0; nt < 4; ++nt)
                    #pragma unroll
                    for (int r = 0; r < 4; ++r) {
                        const int kc = kb + nt * 16 + quad * 4 + r;
                        if (kc > qg) sacc[nt][r] = -1.0e30f;
                    }
            }

            // fixed-base softmax: e = 2^S (base cancels in p = e/l)
            #pragma unroll
            for (int nt = 0; nt < 4; ++nt)
                #pragma unroll
                for (int r = 0; r < 4; ++r) {
                    const float e = __builtin_amdgcn_exp2f(sacc[nt][r]);
                    sacc[nt][r] = e;
                    e_max  = fmaxf(e_max, e);
                    l_lane += e;
                }

            // P: C-layout -> A-layout via swizzled per-wave LDS; perm-packed bf16
            unsigned short* P = &Psh[wave][0];
            #pragma unroll
            for (int nt = 0; nt < 4; ++nt) {
                u32x2 pk;
                pk[0] = pkbf(sacc[nt][0], sacc[nt][1]);
                pk[1] = pkbf(sacc[nt][2], sacc[nt][3]);
                const int g = nt * 2 + (quad >> 1);
                *(u32x2*)&P[m16 * 64 + ((g ^ m7) * 8) + (quad & 1) * 4] = pk;
            }
            bf16x8 pf0 = *(const bf16x8*)&P[m16 * 64 + gsw0];
            bf16x8 pf1 = *(const bf16x8*)&P[m16 * 64 + gsw1];

            // O += E V (unnormalized)
            #pragma unroll
            for (int dt = 0; dt < 4; ++dt) {
                const int rb = (dt * 16 + m16) * 64;
                bf16x8 vf0 = *(const bf16x8*)&Vt[rb + gsw0];
                bf16x8 vf1 = *(const bf16x8*)&Vt[rb + gsw1];
                Oacc[dt] = __builtin_amdgcn_mfma_f32_16x16x32_bf16(pf0, vf0, Oacc[dt], 0, 0, 0);
                Oacc[dt] = __builtin_amdgcn_mfma_f32_16x16x32_bf16(pf1, vf1, Oacc[dt], 0, 0, 0);
            }

            // commit prefetched tile (vmcnt wait lands here, after full tile of compute)
            if (pf) {
                *(u16x8*)&Ksh[b ^ 1][lds0] = kp0; *(u16x8*)&Ksh[b ^ 1][lds1] = kp1;
                *(u16x8*)&Vsh[b ^ 1][lds0] = vp0; *(u16x8*)&Vsh[b ^ 1][lds1] = vp1;
            }
            __syncthreads();
        }

        // per-pass epilogue: reduce l / e_max, normalize, store
        float l = l_lane;
        l += __shfl_xor(l, 16);
        l += __shfl_xor(l, 32);
        float em = e_max;
        em = fmaxf(em, __shfl_xor(em, 16));
        em = fmaxf(em, __shfl_xor(em, 32));
        amax_s = fmaxf(amax_s, em / l);

        #pragma unroll
        for (int r = 0; r < 4; ++r) {
            const float lr  = __shfl(l, (lane & 48) | (quad * 4 + r));
            const float ivl = ss_ / lr;
            const int row = qb + wave * 16 + quad * 4 + r;
            float* op = out + base + (size_t)row * DD + m16;
            #pragma unroll
            for (int dt = 0; dt < 4; ++dt) {
                const float o_raw = Oacc[dt][r] * ivl;
                amax_o = fmaxf(amax_o, fabsf(o_raw));
                op[dt * 16] = o_raw * o_q;
            }
        }
    }

    // one-time amax reduction + atomics
    #pragma unroll
    for (int m = 1; m < 64; m <<= 1) {
        amax_o = fmaxf(amax_o, __shfl_xor(amax_o, m));
        amax_s = fmaxf(amax_s, __shfl_xor(amax_s, m));
    }
    if (lane == 0) {
        atomicMaxPosF(out + OSIZE,     amax_s);
        atomicMaxPosF(out + OSIZE + 1, amax_o);
    }
}

extern "C" void kernel_launch(void* const* d_in, const int* in_sizes, int n_in,
                              void* d_out, int out_size, void* d_ws, size_t ws_size,
                              hipStream_t stream) {
    const float* q   = (const float*)d_in[0];
    const float* k   = (const float*)d_in[1];
    const float* v   = (const float*)d_in[2];
    const float* dsq = (const float*)d_in[3];
    const float* dsk = (const float*)d_in[4];
    const float* dsv = (const float*)d_in[5];
    const float* qss = (const float*)d_in[6];
    const float* qso = (const float*)d_in[7];
    const float* dss = (const float*)d_in[8];
    float* out = (float*)d_out;

    unsigned short* kbf = (unsigned short*)d_ws;            // 8 MB
    unsigned short* vtb = (unsigned short*)d_ws + OSIZE;    // 8 MB

    prep_kv_kernel<<<dim3(SS / 64, BB * HH), 256, 0, stream>>>(k, v, dsk, dsv, kbf, vtb, out);

    dim3 grid(16, BB * HH);   // 512 blocks, each does qt = x and 31-x (33 tiles)
    fattn_kernel<<<grid, 256, 0, stream>>>(q, kbf, vtb, dsq, qss, qso, dss, out);
}

// Round 8
// 178.003 us; speedup vs baseline: 1.8576x; 1.0363x over previous
//
#include <hip/hip_runtime.h>

#define BB 2
#define HH 16
#define SS 2048
#define DD 64

constexpr int OSIZE = BB * HH * SS * DD;  // 4,194,304
constexpr float LOG2E = 1.4426950408889634f;

using bf16x8 = __attribute__((ext_vector_type(8))) short;
using f32x4  = __attribute__((ext_vector_type(4))) float;
using u16x8  = __attribute__((ext_vector_type(8))) unsigned short;
using u32x2  = __attribute__((ext_vector_type(2))) unsigned int;
using fl4    = __attribute__((ext_vector_type(4))) float;

__device__ __forceinline__ unsigned short f2bf(float f) {
    unsigned int u = __float_as_uint(f);
    return (unsigned short)((u + 0x7fffu + ((u >> 16) & 1u)) >> 16);
}

// pack two fp32 -> (bf16_hi<<16)|bf16_lo via one v_perm_b32 (truncation)
__device__ __forceinline__ unsigned int pkbf(float lo, float hi) {
    return __builtin_amdgcn_perm(__float_as_uint(hi), __float_as_uint(lo), 0x07060302u);
}

__device__ __forceinline__ void atomicMaxPosF(float* addr, float v) {
    atomicMax(reinterpret_cast<unsigned int*>(addr), __float_as_uint(v));
}

// ---- fused prepass: amax init + K->bf16 convert + V->bf16 transpose ----
__global__ __launch_bounds__(256) void prep_kv_kernel(
    const float* __restrict__ k, const float* __restrict__ v,
    const float* __restrict__ dsk, const float* __restrict__ dsv,
    unsigned short* __restrict__ kbf, unsigned short* __restrict__ vtb,
    float* __restrict__ out)
{
    const int t  = threadIdx.x;
    const int s0 = blockIdx.x * 64;
    const int bh = blockIdx.y;
    if (blockIdx.x == 0 && bh == 0 && t < 2) out[OSIZE + t] = 0.0f;

    const size_t base = (size_t)bh * SS * DD;
    const float sck = dsk[0], scv = dsv[0];

    // K convert: 64x64 chunk, 16 contiguous elems/thread
    {
        const float* kp = k + base + (size_t)s0 * DD + t * 16;
        unsigned short* ko = kbf + base + (size_t)s0 * DD + t * 16;
        fl4 a0 = ((const fl4*)kp)[0], a1 = ((const fl4*)kp)[1];
        fl4 a2 = ((const fl4*)kp)[2], a3 = ((const fl4*)kp)[3];
        u16x8 o0, o1;
        #pragma unroll
        for (int j = 0; j < 4; ++j) {
            o0[j] = f2bf(a0[j] * sck); o0[j + 4] = f2bf(a1[j] * sck);
            o1[j] = f2bf(a2[j] * sck); o1[j + 4] = f2bf(a3[j] * sck);
        }
        ((u16x8*)ko)[0] = o0; ((u16x8*)ko)[1] = o1;
    }

    // V transpose via LDS: [s][d] -> [d][s]
    __shared__ unsigned short T[64 * 72];
    {
        const int r  = t >> 2;
        const int cb = (t & 3) * 16;
        const fl4* vp = (const fl4*)(v + base + (size_t)(s0 + r) * DD + cb);
        unsigned short tmp[16];
        #pragma unroll
        for (int c = 0; c < 4; ++c) {
            fl4 x = vp[c];
            #pragma unroll
            for (int j = 0; j < 4; ++j) tmp[c * 4 + j] = f2bf(x[j] * scv);
        }
        *(u16x8*)&T[r * 72 + cb]     = *(u16x8*)&tmp[0];
        *(u16x8*)&T[r * 72 + cb + 8] = *(u16x8*)&tmp[8];
    }
    __syncthreads();
    {
        const int dr = t >> 2;
        const int sb = (t & 3) * 16;
        unsigned short tmp[16];
        #pragma unroll
        for (int j = 0; j < 16; ++j) tmp[j] = T[(sb + j) * 72 + dr];
        unsigned short* op = vtb + base + (size_t)dr * SS + s0 + sb;
        *(u16x8*)op       = *(u16x8*)&tmp[0];
        *(u16x8*)(op + 8) = *(u16x8*)&tmp[8];
    }
}

// ---- main kernel: 512 thr, split-K wave groups (even/odd tiles), XCD-local grid ----
__global__ __launch_bounds__(512, 4) void fattn_kernel(
    const float* __restrict__ q,
    const unsigned short* __restrict__ kbf,     // bf16 K  [bh][s][d], dsk folded
    const unsigned short* __restrict__ vtb,     // bf16 V^T [bh][d][s], dsv folded
    const float* __restrict__ dsq, const float* __restrict__ qss,
    const float* __restrict__ qso, const float* __restrict__ dss,
    float* __restrict__ out)
{
    const int bh = blockIdx.x;                  // 0..31  (flat%8 == bh%8 -> XCD-local K/V)
    const int x  = blockIdx.y;                  // 0..15  (qt pair {x, 31-x})
    const int tid   = threadIdx.x;
    const int group = tid >> 8;                 // 0: even k-tiles, 1: odd k-tiles
    const int tg    = tid & 255;                // thread-in-group
    const int wave  = tid >> 6;                 // 0..7
    const int gw    = wave & 3;                 // wave-in-group (q-strip owner)
    const int lane  = tid & 63;
    const int m16   = lane & 15;
    const int quad  = lane >> 4;
    const int m7    = m16 & 7;

    // LDS: per-group K dbuf 16K + V dbuf 16K, P 8x2K = 81920 B total -> 2 blocks/CU
    __shared__ __align__(16) unsigned short Ksh[2][2][64 * 64];
    __shared__ __align__(16) unsigned short Vsh[2][2][64 * 64];
    __shared__ __align__(16) unsigned short Psh[8][16 * 64];

    const float q_scale = dsq[0] * 0.125f * LOG2E;
    const size_t base = (size_t)bh * SS * DD;
    const unsigned short* kbh = kbf + base;
    const unsigned short* vbh = vtb + base;

    // cooperative staging geometry (XOR-swizzled source granule), per group
    const int kr0  = tg >> 3;
    const int kcs  = ((tg & 7) ^ (kr0 & 7)) * 8;
    const int koff0 = kr0 * DD + kcs, koff1 = koff0 + 32 * DD;
    const int voff0 = kr0 * SS + kcs, voff1 = voff0 + 32 * SS;
    const int lds0 = tg * 8, lds1 = (tg + 256) * 8;

    const int gsw0 = (quad ^ m7) * 8;          // swizzled frag-read offsets
    const int gsw1 = ((4 | quad) ^ m7) * 8;

    const float ss_ = qss[0] * dss[0];
    const float o_q = qso[0];
    float amax_o = 0.0f, amax_s = 0.0f;

    float* CombO = (float*)&Ksh[1][0][0];      // 16KB: 4 waves x 4KB (group1 O)
    float* CombL = (float*)&Vsh[1][0][0];      // l / e_max slots

    for (int pass = 0; pass < 2; ++pass) {
        const int qt = pass ? (31 - x) : x;     // pair = 33 tiles, uniform per block
        const int qb = qt * 64;
        const int nkt = qt + 1;
        const int n_iter = (nkt + 1) >> 1;

        // Q fragment (B operand), prescaled — both groups use same q-strips
        bf16x8 qf[2];
        {
            const int qrow = qb + gw * 16 + m16;
            const float* qp = q + base + (size_t)qrow * DD + quad * 8;
            #pragma unroll
            for (int f = 0; f < 2; ++f) {
                fl4 a = *(const fl4*)(qp + f * 32);
                fl4 b = *(const fl4*)(qp + f * 32 + 4);
                #pragma unroll
                for (int j = 0; j < 4; ++j) {
                    qf[f][j]     = (short)f2bf(a[j] * q_scale);
                    qf[f][j + 4] = (short)f2bf(b[j] * q_scale);
                }
            }
        }

        f32x4 Oacc[4];
        #pragma unroll
        for (int dt = 0; dt < 4; ++dt)
            #pragma unroll
            for (int r = 0; r < 4; ++r) Oacc[dt][r] = 0.0f;
        float l_lane = 0.0f, e_max = 0.0f;

        // prologue: group g stages tile g into its buffer 0
        if (group < nkt) {
            const unsigned short* kg = kbh + (size_t)group * 64 * DD;
            const unsigned short* vg = vbh + group * 64;
            u16x8 k0 = *(const u16x8*)(kg + koff0);
            u16x8 k1 = *(const u16x8*)(kg + koff1);
            u16x8 v0 = *(const u16x8*)(vg + voff0);
            u16x8 v1 = *(const u16x8*)(vg + voff1);
            *(u16x8*)&Ksh[group][0][lds0] = k0; *(u16x8*)&Ksh[group][0][lds1] = k1;
            *(u16x8*)&Vsh[group][0][lds0] = v0; *(u16x8*)&Vsh[group][0][lds1] = v1;
        }
        __syncthreads();

        for (int j = 0; j < n_iter; ++j) {
            const int b  = j & 1;
            const int tt = 2 * j + group;       // this group's tile
            const int tn = tt + 2;
            const bool pfv = (tn < nkt);

            u16x8 kp0, kp1, vp0, vp1;
            if (pfv) {
                const unsigned short* kg = kbh + (size_t)tn * 64 * DD;
                const unsigned short* vg = vbh + tn * 64;
                kp0 = *(const u16x8*)(kg + koff0);
                kp1 = *(const u16x8*)(kg + koff1);
                vp0 = *(const u16x8*)(vg + voff0);
                vp1 = *(const u16x8*)(vg + voff1);
            }

            if (tt < nkt) {
                const unsigned short* Kt = &Ksh[group][b][0];
                const unsigned short* Vt = &Vsh[group][b][0];

                // S^T = K Q^T : C[row=k=quad*4+r][col=q=m16]
                f32x4 sacc[4];
                #pragma unroll
                for (int nt = 0; nt < 4; ++nt) {
                    f32x4 acc = {0.0f, 0.0f, 0.0f, 0.0f};
                    const int rb = (nt * 16 + m16) * 64;
                    bf16x8 kf0 = *(const bf16x8*)&Kt[rb + gsw0];
                    bf16x8 kf1 = *(const bf16x8*)&Kt[rb + gsw1];
                    acc = __builtin_amdgcn_mfma_f32_16x16x32_bf16(kf0, qf[0], acc, 0, 0, 0);
                    acc = __builtin_amdgcn_mfma_f32_16x16x32_bf16(kf1, qf[1], acc, 0, 0, 0);
                    sacc[nt] = acc;
                }

                // causal mask (diagonal tile belongs to group (nkt-1)&1)
                if (tt == nkt - 1) {
                    const int qg = qb + gw * 16 + m16;
                    const int kb = tt * 64;
                    #pragma unroll
                    for (int nt = 0; nt < 4; ++nt)
                        #pragma unroll
                        for (int r = 0; r < 4; ++r) {
                            const int kc = kb + nt * 16 + quad * 4 + r;
                            if (kc > qg) sacc[nt][r] = -1.0e30f;
                        }
                }

                // fixed-base softmax: e = 2^S (base cancels; partials merge additively)
                #pragma unroll
                for (int nt = 0; nt < 4; ++nt)
                    #pragma unroll
                    for (int r = 0; r < 4; ++r) {
                        const float e = __builtin_amdgcn_exp2f(sacc[nt][r]);
                        sacc[nt][r] = e;
                        e_max  = fmaxf(e_max, e);
                        l_lane += e;
                    }

                // P: C-layout -> A-layout via swizzled per-wave LDS
                unsigned short* P = &Psh[wave][0];
                #pragma unroll
                for (int nt = 0; nt < 4; ++nt) {
                    u32x2 pk;
                    pk[0] = pkbf(sacc[nt][0], sacc[nt][1]);
                    pk[1] = pkbf(sacc[nt][2], sacc[nt][3]);
                    const int g = nt * 2 + (quad >> 1);
                    *(u32x2*)&P[m16 * 64 + ((g ^ m7) * 8) + (quad & 1) * 4] = pk;
                }
                bf16x8 pf0 = *(const bf16x8*)&P[m16 * 64 + gsw0];
                bf16x8 pf1 = *(const bf16x8*)&P[m16 * 64 + gsw1];

                // O += E V (unnormalized)
                #pragma unroll
                for (int dt = 0; dt < 4; ++dt) {
                    const int rb = (dt * 16 + m16) * 64;
                    bf16x8 vf0 = *(const bf16x8*)&Vt[rb + gsw0];
                    bf16x8 vf1 = *(const bf16x8*)&Vt[rb + gsw1];
                    Oacc[dt] = __builtin_amdgcn_mfma_f32_16x16x32_bf16(pf0, vf0, Oacc[dt], 0, 0, 0);
                    Oacc[dt] = __builtin_amdgcn_mfma_f32_16x16x32_bf16(pf1, vf1, Oacc[dt], 0, 0, 0);
                }
            }

            if (pfv) {  // commit prefetched tile (vmcnt drains after a tile of compute)
                *(u16x8*)&Ksh[group][b ^ 1][lds0] = kp0; *(u16x8*)&Ksh[group][b ^ 1][lds1] = kp1;
                *(u16x8*)&Vsh[group][b ^ 1][lds0] = vp0; *(u16x8*)&Vsh[group][b ^ 1][lds1] = vp1;
            }
            __syncthreads();
        }

        // ---- combine group1 partials into group0 (additive under fixed base) ----
        if (group == 1) {
            float* co = CombO + gw * 1024;
            #pragma unroll
            for (int dt = 0; dt < 4; ++dt) *(f32x4*)(co + dt * 256 + lane * 4) = Oacc[dt];
            CombL[gw * 64 + lane]       = l_lane;
            CombL[256 + gw * 64 + lane] = e_max;
        }
        __syncthreads();
        if (group == 0) {
            const float* co = CombO + gw * 1024;
            #pragma unroll
            for (int dt = 0; dt < 4; ++dt) {
                f32x4 add = *(const f32x4*)(co + dt * 256 + lane * 4);
                #pragma unroll
                for (int r = 0; r < 4; ++r) Oacc[dt][r] += add[r];
            }
            l_lane += CombL[gw * 64 + lane];
            e_max   = fmaxf(e_max, CombL[256 + gw * 64 + lane]);

            float l = l_lane;
            l += __shfl_xor(l, 16);
            l += __shfl_xor(l, 32);
            float em = e_max;
            em = fmaxf(em, __shfl_xor(em, 16));
            em = fmaxf(em, __shfl_xor(em, 32));
            amax_s = fmaxf(amax_s, em / l);

            #pragma unroll
            for (int r = 0; r < 4; ++r) {
                const float lr  = __shfl(l, (lane & 48) | (quad * 4 + r));
                const float ivl = ss_ / lr;
                const int row = qb + gw * 16 + quad * 4 + r;
                float* op = out + base + (size_t)row * DD + m16;
                #pragma unroll
                for (int dt = 0; dt < 4; ++dt) {
                    const float o_raw = Oacc[dt][r] * ivl;
                    amax_o = fmaxf(amax_o, fabsf(o_raw));
                    op[dt * 16] = o_raw * o_q;
                }
            }
        }
        __syncthreads();   // combine reads done before next pass overwrites Ksh/Vsh
    }

    // one-time amax reduction + atomics (group0 only — it holds merged values)
    if (group == 0) {
        #pragma unroll
        for (int m = 1; m < 64; m <<= 1) {
            amax_o = fmaxf(amax_o, __shfl_xor(amax_o, m));
            amax_s = fmaxf(amax_s, __shfl_xor(amax_s, m));
        }
        if (lane == 0) {
            atomicMaxPosF(out + OSIZE,     amax_s);
            atomicMaxPosF(out + OSIZE + 1, amax_o);
        }
    }
}

extern "C" void kernel_launch(void* const* d_in, const int* in_sizes, int n_in,
                              void* d_out, int out_size, void* d_ws, size_t ws_size,
                              hipStream_t stream) {
    const float* q   = (const float*)d_in[0];
    const float* k   = (const float*)d_in[1];
    const float* v   = (const float*)d_in[2];
    const float* dsq = (const float*)d_in[3];
    const float* dsk = (const float*)d_in[4];
    const float* dsv = (const float*)d_in[5];
    const float* qss = (const float*)d_in[6];
    const float* qso = (const float*)d_in[7];
    const float* dss = (const float*)d_in[8];
    float* out = (float*)d_out;

    unsigned short* kbf = (unsigned short*)d_ws;            // 8 MB
    unsigned short* vtb = (unsigned short*)d_ws + OSIZE;    // 8 MB

    prep_kv_kernel<<<dim3(SS / 64, BB * HH), 256, 0, stream>>>(k, v, dsk, dsv, kbf, vtb, out);

    // grid: x = bh (0..31) so flat%8 == bh%8 -> all blocks of a head on one XCD
    dim3 grid(BB * HH, 16);
    fattn_kernel<<<grid, 512, 0, stream>>>(q, kbf, vtb, dsq, qss, qso, dss, out);
}

// Round 10
// 163.316 us; speedup vs baseline: 2.0247x; 1.0899x over previous
//
#include <hip/hip_runtime.h>

#define BB 2
#define HH 16
#define SS 2048
#define DD 64

constexpr int OSIZE = BB * HH * SS * DD;  // 4,194,304
constexpr float LOG2E = 1.4426950408889634f;

using bf16x8 = __attribute__((ext_vector_type(8))) short;
using bf16x4 = __attribute__((ext_vector_type(4))) short;
using f32x4  = __attribute__((ext_vector_type(4))) float;
using u16x8  = __attribute__((ext_vector_type(8))) unsigned short;
using fl4    = __attribute__((ext_vector_type(4))) float;

// gfx950 K=16 bf16 MFMA (v_mfma_f32_16x16x16_bf16): gfx90a+ builtin naming
#define MFMA16(a, b, c) __builtin_amdgcn_mfma_f32_16x16x16bf16_1k(a, b, c, 0, 0, 0)

__device__ __forceinline__ unsigned short f2bf(float f) {
    unsigned int u = __float_as_uint(f);
    return (unsigned short)((u + 0x7fffu + ((u >> 16) & 1u)) >> 16);
}

// pack two fp32 -> (bf16_hi<<16)|bf16_lo via one v_perm_b32 (truncation)
__device__ __forceinline__ unsigned int pkbf(float lo, float hi) {
    return __builtin_amdgcn_perm(__float_as_uint(hi), __float_as_uint(lo), 0x07060302u);
}

__device__ __forceinline__ void atomicMaxPosF(float* addr, float v) {
    atomicMax(reinterpret_cast<unsigned int*>(addr), __float_as_uint(v));
}

// ---- fused prepass: amax init + K->bf16 convert + V->bf16 transpose ----
__global__ __launch_bounds__(256) void prep_kv_kernel(
    const float* __restrict__ k, const float* __restrict__ v,
    const float* __restrict__ dsk, const float* __restrict__ dsv,
    unsigned short* __restrict__ kbf, unsigned short* __restrict__ vtb,
    float* __restrict__ out)
{
    const int t  = threadIdx.x;
    const int s0 = blockIdx.x * 64;
    const int bh = blockIdx.y;
    if (blockIdx.x == 0 && bh == 0 && t < 2) out[OSIZE + t] = 0.0f;

    const size_t base = (size_t)bh * SS * DD;
    const float sck = dsk[0], scv = dsv[0];

    {
        const float* kp = k + base + (size_t)s0 * DD + t * 16;
        unsigned short* ko = kbf + base + (size_t)s0 * DD + t * 16;
        fl4 a0 = ((const fl4*)kp)[0], a1 = ((const fl4*)kp)[1];
        fl4 a2 = ((const fl4*)kp)[2], a3 = ((const fl4*)kp)[3];
        u16x8 o0, o1;
        #pragma unroll
        for (int j = 0; j < 4; ++j) {
            o0[j] = f2bf(a0[j] * sck); o0[j + 4] = f2bf(a1[j] * sck);
            o1[j] = f2bf(a2[j] * sck); o1[j + 4] = f2bf(a3[j] * sck);
        }
        ((u16x8*)ko)[0] = o0; ((u16x8*)ko)[1] = o1;
    }

    __shared__ unsigned short T[64 * 72];
    {
        const int r  = t >> 2;
        const int cb = (t & 3) * 16;
        const fl4* vp = (const fl4*)(v + base + (size_t)(s0 + r) * DD + cb);
        unsigned short tmp[16];
        #pragma unroll
        for (int c = 0; c < 4; ++c) {
            fl4 xx = vp[c];
            #pragma unroll
            for (int j = 0; j < 4; ++j) tmp[c * 4 + j] = f2bf(xx[j] * scv);
        }
        *(u16x8*)&T[r * 72 + cb]     = *(u16x8*)&tmp[0];
        *(u16x8*)&T[r * 72 + cb + 8] = *(u16x8*)&tmp[8];
    }
    __syncthreads();
    {
        const int dr = t >> 2;
        const int sb = (t & 3) * 16;
        unsigned short tmp[16];
        #pragma unroll
        for (int j = 0; j < 16; ++j) tmp[j] = T[(sb + j) * 72 + dr];
        unsigned short* op = vtb + base + (size_t)dr * SS + s0 + sb;
        *(u16x8*)op       = *(u16x8*)&tmp[0];
        *(u16x8*)(op + 8) = *(u16x8*)&tmp[8];
    }
}

// ---- main kernel: k-split waves, no P roundtrip, per-pass O reduction ----
__global__ __launch_bounds__(512, 4) void fattn_kernel(
    const float* __restrict__ q,
    const unsigned short* __restrict__ kbf,     // bf16 K  [bh][s][d], dsk folded
    const unsigned short* __restrict__ vtb,     // bf16 V^T [bh][d][s], dsv folded
    const float* __restrict__ dsq, const float* __restrict__ qss,
    const float* __restrict__ qso, const float* __restrict__ dss,
    float* __restrict__ out)
{
    const int bh = blockIdx.x;                  // flat%8 == bh%8 -> XCD-local K/V
    const int x  = blockIdx.y;                  // 0..15 (qt pair {x, 31-x})
    const int tid  = threadIdx.x;
    const int wave = tid >> 6;
    const int qh   = wave >> 2;                 // q-half (0,1): q rows qh*32..+32
    const int ks   = wave & 3;                  // k-slice: k rows ks*16..+16
    const int lane = tid & 63;
    const int m16  = lane & 15;
    const int quad = lane >> 4;
    const int m7   = m16 & 7;

    // LDS: KV dbuf 32 KB (overlaid by O-reduction scratch) + Lred/Ered 2 KB
    __shared__ __align__(16) unsigned short KV[2][2][64 * 64];  // [k/v][buf]
    __shared__ float Lred[2][4][2][16];   // [qh][ks][nt][m16]
    __shared__ float Ered[2][4][2][16];

    const float q_scale = dsq[0] * 0.125f * LOG2E;
    const size_t base = (size_t)bh * SS * DD;
    const unsigned short* kbh = kbf + base;
    const unsigned short* vbh = vtb + base;

    // staging: one 16B granule of K and V per thread, XOR-swizzled source col
    const int srow = tid >> 3;
    const int sgc  = (tid & 7) ^ (srow & 7);
    const int koff = srow * DD + sgc * 8;
    const int voff = srow * SS + sgc * 8;
    const int ldso = tid * 8;

    // fragment read offsets (swizzled granules)
    const int gsw0 = (quad ^ m7) * 8;
    const int gsw1 = ((4 | quad) ^ m7) * 8;
    const int krow = (ks * 16 + m16) * 64;
    const int vg   = ks * 2 + (quad >> 1);
    const int vsw  = ((vg ^ m7) * 8) + (quad & 1) * 4;

    const float ss_ = qss[0] * dss[0];
    const float o_q = qso[0];
    float amax_o = 0.0f, amax_s = 0.0f;

    float* Ored = (float*)&KV[0][0][0];   // 32 KB overlay, 4 slices x 8 KB

    for (int pass = 0; pass < 2; ++pass) {
        const int qt = pass ? (31 - x) : x;
        const int qb = qt * 64;
        const int nkt = qt + 1;

        // Q fragments (B operand) for this wave's 2 q-tiles, prescaled
        bf16x8 qf[2][2];
        #pragma unroll
        for (int nt = 0; nt < 2; ++nt) {
            const float* qp = q + base + (size_t)(qb + qh * 32 + nt * 16 + m16) * DD + quad * 8;
            #pragma unroll
            for (int f = 0; f < 2; ++f) {
                fl4 a = *(const fl4*)(qp + f * 32);
                fl4 b2 = *(const fl4*)(qp + f * 32 + 4);
                #pragma unroll
                for (int j = 0; j < 4; ++j) {
                    qf[nt][f][j]     = (short)f2bf(a[j] * q_scale);
                    qf[nt][f][j + 4] = (short)f2bf(b2[j] * q_scale);
                }
            }
        }

        f32x4 Oacc[4][2];   // O^T partial: [dt][nt], row d=dt*16+quad*4+r, col q=nt*16+m16 (+qh*32)
        #pragma unroll
        for (int dt = 0; dt < 4; ++dt)
            #pragma unroll
            for (int nt = 0; nt < 2; ++nt)
                #pragma unroll
                for (int r = 0; r < 4; ++r) Oacc[dt][nt][r] = 0.0f;
        float l_l[2] = {0.0f, 0.0f}, e_m[2] = {0.0f, 0.0f};

        // stage tile 0
        {
            u16x8 kk = *(const u16x8*)(kbh + koff);
            u16x8 vv = *(const u16x8*)(vbh + voff);
            *(u16x8*)&KV[0][0][ldso] = kk;
            *(u16x8*)&KV[1][0][ldso] = vv;
        }
        __syncthreads();

        for (int t = 0; t < nkt; ++t) {
            const int b = t & 1;
            const bool pf = (t + 1 < nkt);

            u16x8 kpf, vpf;
            if (pf) {
                kpf = *(const u16x8*)(kbh + (size_t)(t + 1) * 64 * DD + koff);
                vpf = *(const u16x8*)(vbh + (t + 1) * 64 + voff);
            }

            const unsigned short* Kt = &KV[0][b][0];
            const unsigned short* Vt = &KV[1][b][0];

            // S^T slice = K(ks rows) Q^T : C[row=k=quad*4+r][col=q=m16], per q-tile nt
            bf16x8 kf0 = *(const bf16x8*)&Kt[krow + gsw0];
            bf16x8 kf1 = *(const bf16x8*)&Kt[krow + gsw1];
            f32x4 sacc[2];
            #pragma unroll
            for (int nt = 0; nt < 2; ++nt) {
                f32x4 acc = {0.0f, 0.0f, 0.0f, 0.0f};
                acc = __builtin_amdgcn_mfma_f32_16x16x32_bf16(kf0, qf[nt][0], acc, 0, 0, 0);
                acc = __builtin_amdgcn_mfma_f32_16x16x32_bf16(kf1, qf[nt][1], acc, 0, 0, 0);
                sacc[nt] = acc;
            }

            // causal mask on the diagonal tile
            if (t == nkt - 1) {
                const int kgb = t * 64 + ks * 16 + quad * 4;
                #pragma unroll
                for (int nt = 0; nt < 2; ++nt) {
                    const int qg = qb + qh * 32 + nt * 16 + m16;
                    #pragma unroll
                    for (int r = 0; r < 4; ++r)
                        if (kgb + r > qg) sacc[nt][r] = -1.0e30f;
                }
            }

            // fixed-base softmax + pack P^T straight into the 16x16x16 B operand
            bf16x4 pb[2];
            #pragma unroll
            for (int nt = 0; nt < 2; ++nt) {
                #pragma unroll
                for (int r = 0; r < 4; ++r) {
                    const float e = __builtin_amdgcn_exp2f(sacc[nt][r]);
                    sacc[nt][r] = e;
                    l_l[nt] += e;
                    e_m[nt] = fmaxf(e_m[nt], e);
                }
                union { unsigned int u[2]; bf16x4 h; } cv;
                cv.u[0] = pkbf(sacc[nt][0], sacc[nt][1]);
                cv.u[1] = pkbf(sacc[nt][2], sacc[nt][3]);
                pb[nt] = cv.h;
            }

            // O^T += V^T(k-slice) P^T : A = V^T[d][k], B = P^T[k][q] (identity layout!)
            #pragma unroll
            for (int dt = 0; dt < 4; ++dt) {
                bf16x4 vf = *(const bf16x4*)&Vt[(dt * 16 + m16) * 64 + vsw];
                #pragma unroll
                for (int nt = 0; nt < 2; ++nt)
                    Oacc[dt][nt] = MFMA16(vf, pb[nt], Oacc[dt][nt]);
            }

            if (pf) {
                *(u16x8*)&KV[0][b ^ 1][ldso] = kpf;
                *(u16x8*)&KV[1][b ^ 1][ldso] = vpf;
            }
            __syncthreads();
        }

        // ---- per-pass reductions ----
        // l/e: sum/max over quads (k within slice), publish per (qh,ks,nt,m16)
        #pragma unroll
        for (int nt = 0; nt < 2; ++nt) {
            l_l[nt] += __shfl_xor(l_l[nt], 16);
            l_l[nt] += __shfl_xor(l_l[nt], 32);
            e_m[nt] = fmaxf(e_m[nt], __shfl_xor(e_m[nt], 16));
            e_m[nt] = fmaxf(e_m[nt], __shfl_xor(e_m[nt], 32));
        }
        if (quad == 0) {
            #pragma unroll
            for (int nt = 0; nt < 2; ++nt) {
                Lred[qh][ks][nt][m16] = l_l[nt];
                Ered[qh][ks][nt][m16] = e_m[nt];
            }
        }

        // O tree-reduction over k-slices via LDS overlay (swizzled, conflict-free)
        const int lsw = lane * 32;
        if (ks >= 2) {
            const int s = (qh * 2 + (ks - 2)) * 2048;
            #pragma unroll
            for (int i = 0; i < 8; ++i)
                *(f32x4*)&Ored[s + lsw + ((i ^ (lane & 7)) << 2)] = Oacc[i >> 1][i & 1];
        }
        __syncthreads();
        if (ks < 2) {
            const int s = (qh * 2 + ks) * 2048;
            #pragma unroll
            for (int i = 0; i < 8; ++i) {
                f32x4 a = *(const f32x4*)&Ored[s + lsw + ((i ^ (lane & 7)) << 2)];
                #pragma unroll
                for (int r = 0; r < 4; ++r) Oacc[i >> 1][i & 1][r] += a[r];
            }
        }
        if (ks == 1) {
            const int s = (qh * 2 + 1) * 2048;
            #pragma unroll
            for (int i = 0; i < 8; ++i)
                *(f32x4*)&Ored[s + lsw + ((i ^ (lane & 7)) << 2)] = Oacc[i >> 1][i & 1];
        }
        __syncthreads();
        if (ks == 0) {
            const int s = (qh * 2 + 1) * 2048;
            #pragma unroll
            for (int i = 0; i < 8; ++i) {
                f32x4 a = *(const f32x4*)&Ored[s + lsw + ((i ^ (lane & 7)) << 2)];
                #pragma unroll
                for (int r = 0; r < 4; ++r) Oacc[i >> 1][i & 1][r] += a[r];
            }
            // final l / e over k-slices, then normalize + store + amax
            #pragma unroll
            for (int nt = 0; nt < 2; ++nt) {
                float lq = Lred[qh][0][nt][m16] + Lred[qh][1][nt][m16]
                         + Lred[qh][2][nt][m16] + Lred[qh][3][nt][m16];
                float eq = fmaxf(fmaxf(Ered[qh][0][nt][m16], Ered[qh][1][nt][m16]),
                                 fmaxf(Ered[qh][2][nt][m16], Ered[qh][3][nt][m16]));
                amax_s = fmaxf(amax_s, eq / lq);
                const float ivl = ss_ / lq;
                float* oprow = out + base + (size_t)(qb + qh * 32 + nt * 16 + m16) * DD + quad * 4;
                #pragma unroll
                for (int dt = 0; dt < 4; ++dt) {
                    f32x4 ov;
                    #pragma unroll
                    for (int r = 0; r < 4; ++r) {
                        const float o_raw = Oacc[dt][nt][r] * ivl;
                        amax_o = fmaxf(amax_o, fabsf(o_raw));
                        ov[r] = o_raw * o_q;
                    }
                    *(f32x4*)(oprow + dt * 16) = ov;
                }
            }
        }
        __syncthreads();   // LDS reusable for next pass
    }

    if (ks == 0) {
        #pragma unroll
        for (int m = 1; m < 64; m <<= 1) {
            amax_o = fmaxf(amax_o, __shfl_xor(amax_o, m));
            amax_s = fmaxf(amax_s, __shfl_xor(amax_s, m));
        }
        if (lane == 0) {
            atomicMaxPosF(out + OSIZE,     amax_s);
            atomicMaxPosF(out + OSIZE + 1, amax_o);
        }
    }
}

extern "C" void kernel_launch(void* const* d_in, const int* in_sizes, int n_in,
                              void* d_out, int out_size, void* d_ws, size_t ws_size,
                              hipStream_t stream) {
    const float* q   = (const float*)d_in[0];
    const float* k   = (const float*)d_in[1];
    const float* v   = (const float*)d_in[2];
    const float* dsq = (const float*)d_in[3];
    const float* dsk = (const float*)d_in[4];
    const float* dsv = (const float*)d_in[5];
    const float* qss = (const float*)d_in[6];
    const float* qso = (const float*)d_in[7];
    const float* dss = (const float*)d_in[8];
    float* out = (float*)d_out;

    unsigned short* kbf = (unsigned short*)d_ws;            // 8 MB
    unsigned short* vtb = (unsigned short*)d_ws + OSIZE;    // 8 MB

    prep_kv_kernel<<<dim3(SS / 64, BB * HH), 256, 0, stream>>>(k, v, dsk, dsv, kbf, vtb, out);

    // grid: x = bh so flat%8 == bh%8 -> all blocks of a head on one XCD
    dim3 grid(BB * HH, 16);
    fattn_kernel<<<grid, 512, 0, stream>>>(q, kbf, vtb, dsq, qss, qso, dss, out);
}